// Round 4
// baseline (561.676 us; speedup 1.0000x reference)
//
#include <hip/hip_runtime.h>

// Problem constants
#define B_N 4096
#define T_N 512
// Output layout (floats): final (B,T,2) | fwd_out (B,2) | noise (B,T,1)
#define FWD_OFF   (B_N * T_N * 2)        // 4194304
#define NOISE_OFF (FWD_OFF + B_N * 2)    // 4202496

#define S_SIG  (-1.4426950408889634f)   // -log2(e)
#define S_TANH (-2.8853900817779268f)   // -2*log2(e)

// act on pre-scaled accumulator: fma(A, rcp(1+exp2(a)), B)
// A=1,B=0  -> sigmoid(v), a = -log2e*v
// A=2,B=-1 -> tanh(v),    a = -2log2e*v
__device__ __forceinline__ float act_ab(float a, float A, float Bc) {
    float r = __builtin_amdgcn_rcpf(1.0f + __builtin_amdgcn_exp2f(a));
    return fmaf(A, r, Bc);
}
__device__ __forceinline__ float sig_acc(float a) {
    return __builtin_amdgcn_rcpf(1.0f + __builtin_amdgcn_exp2f(a));
}
__device__ __forceinline__ float tanh_acc(float a) {
    return fmaf(2.0f, __builtin_amdgcn_rcpf(1.0f + __builtin_amdgcn_exp2f(a)), -1.0f);
}
__device__ __forceinline__ float tanh_nat(float v) {
    return tanh_acc(v * S_TANH);
}

// 32 lanes per batch element. Grid = 4096*32 = 131072 threads = 2048 waves
// = 2 waves/SIMD chip-wide. launch_bounds(256,2): VGPR budget 256.
__global__ __launch_bounds__(256, 2)
void fused_kernel(
    const float* __restrict__ x,
    const float* __restrict__ eWih0, const float* __restrict__ eWhh0,
    const float* __restrict__ ebih0, const float* __restrict__ ebhh0,
    const float* __restrict__ eWih1, const float* __restrict__ eWhh1,
    const float* __restrict__ ebih1, const float* __restrict__ ebhh1,
    const float* __restrict__ dWih0, const float* __restrict__ dWhh0,
    const float* __restrict__ dbih0, const float* __restrict__ dbhh0,
    const float* __restrict__ dWih1, const float* __restrict__ dWhh1,
    const float* __restrict__ dbih1, const float* __restrict__ dbhh1,
    const float* __restrict__ fcW, const float* __restrict__ fcb,
    const float* __restrict__ outW, const float* __restrict__ outb,
    float* __restrict__ out)
{
    const int tid    = blockIdx.x * 256 + threadIdx.x;
    const int b      = tid >> 5;      // batch element
    const int lane32 = tid & 31;      // 32 lanes per element

    // =================== ENCODER: gate-row-parallel (H=4) ===================
    // row r = lane32 & 15; lanes 16..31 redundantly duplicate lanes 0..15,
    // which leaves identical state in both halves for the decoder handoff.
    const int r16 = lane32 & 15;
    const int u4 = r16 & 3;
    const int kk = r16 >> 2;
    const float sc = (kk == 2) ? S_TANH : S_SIG;
    const float Ak = (kk == 2) ? 2.0f : 1.0f;
    const float Bk = (kk == 2) ? -1.0f : 0.0f;

    float h0v[4] = {0.f, 0.f, 0.f, 0.f};
    float h1v[4] = {0.f, 0.f, 0.f, 0.f};
    float c0 = 0.f, c1 = 0.f;
    float fw0, fw1;

    {
        float ew0 = eWih0[r16] * sc;
        float eb0 = (ebih0[r16] + ebhh0[r16]) * sc;
        float eb1 = (ebih1[r16] + ebhh1[r16]) * sc;
        float ewh0[4], ewi1[4], ewh1[4];
#pragma unroll
        for (int j = 0; j < 4; ++j) {
            ewh0[j] = eWhh0[r16 * 4 + j] * sc;
            ewi1[j] = eWih1[r16 * 4 + j] * sc;
            ewh1[j] = eWhh1[r16 * 4 + j] * sc;
        }

        const float4* __restrict__ xq4 = (const float4*)(x + (long)b * T_N);
        float4 xq = xq4[0];

        auto estep = [&](float xc) {
            float p = eb1;
#pragma unroll
            for (int j = 0; j < 4; ++j) p = fmaf(ewh1[j], h1v[j], p);

            float g = fmaf(ew0, xc, eb0);
#pragma unroll
            for (int j = 0; j < 4; ++j) g = fmaf(ewh0[j], h0v[j], g);
            float gate = act_ab(g, Ak, Bk);
            float fv = __shfl(gate, u4 + 4, 16);
            float gv = __shfl(gate, u4 + 8, 16);
            float ov = __shfl(gate, u4 + 12, 16);
            c0 = fmaf(fv, c0, gate * gv);
            float h0u = ov * tanh_nat(c0);
#pragma unroll
            for (int j = 0; j < 4; ++j) h0v[j] = __shfl(h0u, j, 16);

            float q = 0.f;
#pragma unroll
            for (int j = 0; j < 4; ++j) q = fmaf(ewi1[j], h0v[j], q);
            float gate1 = act_ab(p + q, Ak, Bk);
            fv = __shfl(gate1, u4 + 4, 16);
            gv = __shfl(gate1, u4 + 8, 16);
            ov = __shfl(gate1, u4 + 12, 16);
            c1 = fmaf(fv, c1, gate1 * gv);
            float h1u = ov * tanh_nat(c1);
#pragma unroll
            for (int j = 0; j < 4; ++j) h1v[j] = __shfl(h1u, j, 16);
        };

        for (int tb = 0; tb < T_N / 4; ++tb) {
            float4 xn = (tb + 1 < T_N / 4) ? xq4[tb + 1] : xq;  // prefetch
            estep(xq.x); estep(xq.y); estep(xq.z); estep(xq.w);
            xq = xn;
        }

        fw0 = fcb[0];
        fw1 = fcb[1];
#pragma unroll
        for (int j = 0; j < 4; ++j) {
            fw0 = fmaf(fcW[j], h1v[j], fw0);
            fw1 = fmaf(fcW[4 + j], h1v[j], fw1);
        }
        if (lane32 == 0) {
            out[FWD_OFF + b * 2 + 0] = fw0;
            out[FWD_OFF + b * 2 + 1] = fw1;
        }
    }

    // =================== DECODER: gate-pair split (H=10, 32 lanes) ===================
    // lane = (u, s): u = lane32&15 (units 0..9 live, 10..15 shadow), s = lane32>>4.
    // slot s=0 owns gate rows {i (k=0), g (k=2)}; s=1 owns {f (k=1), o (k=3)}.
    // c-state lives on s=1 lanes; i*tanh(g) is local on s=0, one shfl moves it over.
    const int u  = lane32 & 15;
    const int uc = (u < 10) ? u : 9;
    const int s  = lane32 >> 4;

    const int rowA = s * 10 + uc;        // i (s=0) or f (s=1): sigmoid
    const int rowB = (2 + s) * 10 + uc;  // g (s=0) or o (s=1)
    const float scB = s ? S_SIG : S_TANH;
    const float A1  = s ? 1.0f : 2.0f;
    const float B1  = s ? 0.0f : -1.0f;

    float wih0A = dWih0[rowA] * S_SIG;
    float wih0B = dWih0[rowB] * scB;
    float b0A = (dbih0[rowA] + dbhh0[rowA]) * S_SIG;
    float b0B = (dbih0[rowB] + dbhh0[rowB]) * scB;
    float b1A = (dbih1[rowA] + dbhh1[rowA]) * S_SIG;
    float b1B = (dbih1[rowB] + dbhh1[rowB]) * scB;
    float whh0A[10], whh0B[10], wih1A[10], wih1B[10], whh1A[10], whh1B[10];
#pragma unroll
    for (int j = 0; j < 10; ++j) {
        whh0A[j] = dWhh0[rowA * 10 + j] * S_SIG;
        whh0B[j] = dWhh0[rowB * 10 + j] * scB;
        wih1A[j] = dWih1[rowA * 10 + j] * S_SIG;
        wih1B[j] = dWih1[rowB * 10 + j] * scB;
        whh1A[j] = dWhh1[rowA * 10 + j] * S_SIG;
        whh1B[j] = dWhh1[rowB * 10 + j] * scB;
    }
    float outw[10];
#pragma unroll
    for (int j = 0; j < 10; ++j) outw[j] = outW[j];
    const float outb0 = outb[0];

    // Initial decoder state: encoder finals padded 4 -> 10 with zeros.
    float dh0[10], dh1[10];
#pragma unroll
    for (int j = 0; j < 10; ++j) {
        dh0[j] = (j < 4) ? h0v[j] : 0.f;
        dh1[j] = (j < 4) ? h1v[j] : 0.f;
    }
    float dc0 = (u < 4) ? c0 : 0.f;   // valid on s=1 lanes (duplicated encoder state)
    float dc1 = (u < 4) ? c1 : 0.f;

    float my_noise = 0.f;

    for (int t = 0; t < T_N; ++t) {
        const float inp = dh1[0];

        // L1 partials from previous h1 (independent of L0 chain)
        float pA = b1A, pB = b1B;
#pragma unroll
        for (int j = 0; j < 10; ++j) {
            pA = fmaf(whh1A[j], dh1[j], pA);
            pB = fmaf(whh1B[j], dh1[j], pB);
        }

        // L0 gate rows
        float aA = fmaf(wih0A, inp, b0A);
        float aB = fmaf(wih0B, inp, b0B);
#pragma unroll
        for (int j = 0; j < 10; ++j) {
            aA = fmaf(whh0A[j], dh0[j], aA);
            aB = fmaf(whh0B[j], dh0[j], aB);
        }
        float gateA = sig_acc(aA);          // i (s=0) / f (s=1)
        float gateB = act_ab(aB, A1, B1);   // tanh(g) (s=0) / o (s=1)
        float ig  = gateA * gateB;          // i*tanh(g), meaningful on s=0
        float igx = __shfl(ig, u, 32);      // fetch from lane (u, s=0)
        dc0 = fmaf(gateA, dc0, igx);        // s=1: f*c0 + i*g (s=0 garbage, unread)
        float h0u = gateB * tanh_nat(dc0);  // s=1: o * tanh(c0)
#pragma unroll
        for (int j = 0; j < 10; ++j) dh0[j] = __shfl(h0u, 16 + j, 32);

        // L1 gate rows (post-broadcast half)
        float qA = 0.f, qB = 0.f;
#pragma unroll
        for (int j = 0; j < 10; ++j) {
            qA = fmaf(wih1A[j], dh0[j], qA);
            qB = fmaf(wih1B[j], dh0[j], qB);
        }
        gateA = sig_acc(pA + qA);
        gateB = act_ab(pB + qB, A1, B1);
        ig  = gateA * gateB;
        igx = __shfl(ig, u, 32);
        dc1 = fmaf(gateA, dc1, igx);
        float h1u = gateB * tanh_nat(dc1);
#pragma unroll
        for (int j = 0; j < 10; ++j) dh1[j] = __shfl(h1u, 16 + j, 32);

        // noise_t = dec_out . out_W + out_b (uniform on all 32 lanes)
        float nz = outb0;
#pragma unroll
        for (int j = 0; j < 10; ++j) nz = fmaf(outw[j], dh1[j], nz);

        // lane keeps t with t%32==lane32; flush coalesced every 32 steps
        my_noise = ((t & 31) == lane32) ? nz : my_noise;
        if ((t & 31) == 31) {
            const int idx = b * T_N + (t - 31) + lane32;
            out[NOISE_OFF + idx] = my_noise;
            float2 fin;
            fin.x = my_noise + fw0;
            fin.y = my_noise + fw1;
            ((float2*)out)[idx] = fin;
        }
    }
}

extern "C" void kernel_launch(void* const* d_in, const int* in_sizes, int n_in,
                              void* d_out, int out_size, void* d_ws, size_t ws_size,
                              hipStream_t stream) {
    const float* x     = (const float*)d_in[0];
    // d_in[1] = context (unused by the reference)
    const float* eWih0 = (const float*)d_in[2];
    const float* eWhh0 = (const float*)d_in[3];
    const float* ebih0 = (const float*)d_in[4];
    const float* ebhh0 = (const float*)d_in[5];
    const float* eWih1 = (const float*)d_in[6];
    const float* eWhh1 = (const float*)d_in[7];
    const float* ebih1 = (const float*)d_in[8];
    const float* ebhh1 = (const float*)d_in[9];
    const float* dWih0 = (const float*)d_in[10];
    const float* dWhh0 = (const float*)d_in[11];
    const float* dbih0 = (const float*)d_in[12];
    const float* dbhh0 = (const float*)d_in[13];
    const float* dWih1 = (const float*)d_in[14];
    const float* dWhh1 = (const float*)d_in[15];
    const float* dbih1 = (const float*)d_in[16];
    const float* dbhh1 = (const float*)d_in[17];
    const float* fcW   = (const float*)d_in[18];
    const float* fcb   = (const float*)d_in[19];
    const float* outW  = (const float*)d_in[20];
    const float* outb  = (const float*)d_in[21];

    float* out = (float*)d_out;

    // 4096 elems x 32 lanes = 131072 threads = 2048 waves = 2 waves/SIMD
    fused_kernel<<<dim3((B_N * 32) / 256), dim3(256), 0, stream>>>(
        x, eWih0, eWhh0, ebih0, ebhh0, eWih1, eWhh1, ebih1, ebhh1,
        dWih0, dWhh0, dbih0, dbhh0, dWih1, dWhh1, dbih1, dbhh1,
        fcW, fcb, outW, outb, out);
}

// Round 6
// 519.510 us; speedup vs baseline: 1.0812x; 1.0812x over previous
//
#include <hip/hip_runtime.h>

// Problem constants
#define B_N 4096
#define T_N 512
// Output layout (floats): final (B,T,2) | fwd_out (B,2) | noise (B,T,1)
#define FWD_OFF   (B_N * T_N * 2)        // 4194304
#define NOISE_OFF (FWD_OFF + B_N * 2)    // 4202496

#define S_SIG  (-1.4426950408889634f)   // -log2(e)
#define S_TANH (-2.8853900817779268f)   // -2*log2(e)

typedef float v4f __attribute__((ext_vector_type(4)));

// Workspace blob layout (v4f units):
//   decoder: lane u in [0,16): base u*34
//     [0..9]   whh0T[j] : {k0,k1,k2,k3} rows of dWhh0 col j (pre-scaled)
//     [10..19] wih1T[j]
//     [20..29] whh1T[j]
//     [30]     wih0T, [31] b0T, [32] b1T
//     [33]     {outw_u, outb0, 0, 0}
//   encoder: lane r in [0,16): base 544 + r*4
//     [0] ewh0 row, [1] ewi1 row, [2] ewh1 row, [3] {ew0, eb0, eb1, 0}
#define ENC_BASE 544

__device__ __forceinline__ float sig_acc(float a) {
    return __builtin_amdgcn_rcpf(1.0f + __builtin_amdgcn_exp2f(a));
}
__device__ __forceinline__ float tanh_acc(float a) {
    return fmaf(2.0f, __builtin_amdgcn_rcpf(1.0f + __builtin_amdgcn_exp2f(a)), -1.0f);
}
__device__ __forceinline__ float tanh_nat(float v) { return tanh_acc(v * S_TANH); }
__device__ __forceinline__ float act_ab(float a, float A, float Bc) {
    float r = __builtin_amdgcn_rcpf(1.0f + __builtin_amdgcn_exp2f(a));
    return fmaf(A, r, Bc);
}
__device__ __forceinline__ void fma4(v4f& accv, const v4f wv, const float sv) {
    accv.x = fmaf(wv.x, sv, accv.x);
    accv.y = fmaf(wv.y, sv, accv.y);
    accv.z = fmaf(wv.z, sv, accv.z);
    accv.w = fmaf(wv.w, sv, accv.w);
}

// ---------------- Prep: pack pre-scaled transposed weights into ws ----------------
__global__ void prep_kernel(
    const float* __restrict__ eWih0, const float* __restrict__ eWhh0,
    const float* __restrict__ ebih0, const float* __restrict__ ebhh0,
    const float* __restrict__ eWih1, const float* __restrict__ eWhh1,
    const float* __restrict__ ebih1, const float* __restrict__ ebhh1,
    const float* __restrict__ dWih0, const float* __restrict__ dWhh0,
    const float* __restrict__ dbih0, const float* __restrict__ dbhh0,
    const float* __restrict__ dWih1, const float* __restrict__ dWhh1,
    const float* __restrict__ dbih1, const float* __restrict__ dbhh1,
    const float* __restrict__ outW, const float* __restrict__ outb,
    float* __restrict__ ws)
{
    v4f* wsv = (v4f*)ws;
    const int t = threadIdx.x;
    if (t < 16) {
        // decoder lane u
        const int u = t;
        const int uc = (u < 10) ? u : 9;
        const int base = u * 34;
        for (int j = 0; j < 10; ++j) {
            v4f a, bqq, c;
            a.x = dWhh0[(0 * 10 + uc) * 10 + j] * S_SIG;
            a.y = dWhh0[(1 * 10 + uc) * 10 + j] * S_SIG;
            a.z = dWhh0[(2 * 10 + uc) * 10 + j] * S_TANH;
            a.w = dWhh0[(3 * 10 + uc) * 10 + j] * S_SIG;
            bqq.x = dWih1[(0 * 10 + uc) * 10 + j] * S_SIG;
            bqq.y = dWih1[(1 * 10 + uc) * 10 + j] * S_SIG;
            bqq.z = dWih1[(2 * 10 + uc) * 10 + j] * S_TANH;
            bqq.w = dWih1[(3 * 10 + uc) * 10 + j] * S_SIG;
            c.x = dWhh1[(0 * 10 + uc) * 10 + j] * S_SIG;
            c.y = dWhh1[(1 * 10 + uc) * 10 + j] * S_SIG;
            c.z = dWhh1[(2 * 10 + uc) * 10 + j] * S_TANH;
            c.w = dWhh1[(3 * 10 + uc) * 10 + j] * S_SIG;
            wsv[base + j] = a;
            wsv[base + 10 + j] = bqq;
            wsv[base + 20 + j] = c;
        }
        v4f w0, b0, b1, msc;
        w0.x = dWih0[0 * 10 + uc] * S_SIG;
        w0.y = dWih0[1 * 10 + uc] * S_SIG;
        w0.z = dWih0[2 * 10 + uc] * S_TANH;
        w0.w = dWih0[3 * 10 + uc] * S_SIG;
        b0.x = (dbih0[0 * 10 + uc] + dbhh0[0 * 10 + uc]) * S_SIG;
        b0.y = (dbih0[1 * 10 + uc] + dbhh0[1 * 10 + uc]) * S_SIG;
        b0.z = (dbih0[2 * 10 + uc] + dbhh0[2 * 10 + uc]) * S_TANH;
        b0.w = (dbih0[3 * 10 + uc] + dbhh0[3 * 10 + uc]) * S_SIG;
        b1.x = (dbih1[0 * 10 + uc] + dbhh1[0 * 10 + uc]) * S_SIG;
        b1.y = (dbih1[1 * 10 + uc] + dbhh1[1 * 10 + uc]) * S_SIG;
        b1.z = (dbih1[2 * 10 + uc] + dbhh1[2 * 10 + uc]) * S_TANH;
        b1.w = (dbih1[3 * 10 + uc] + dbhh1[3 * 10 + uc]) * S_SIG;
        msc.x = (u < 10) ? outW[u] : 0.f;
        msc.y = outb[0];
        msc.z = 0.f; msc.w = 0.f;
        wsv[base + 30] = w0;
        wsv[base + 31] = b0;
        wsv[base + 32] = b1;
        wsv[base + 33] = msc;
    } else if (t < 32) {
        // encoder lane r
        const int r = t - 16;
        const float sc = ((r >> 2) == 2) ? S_TANH : S_SIG;
        const int base = ENC_BASE + r * 4;
        v4f a, bqq, c, m;
        a.x = eWhh0[r * 4 + 0] * sc; a.y = eWhh0[r * 4 + 1] * sc;
        a.z = eWhh0[r * 4 + 2] * sc; a.w = eWhh0[r * 4 + 3] * sc;
        bqq.x = eWih1[r * 4 + 0] * sc; bqq.y = eWih1[r * 4 + 1] * sc;
        bqq.z = eWih1[r * 4 + 2] * sc; bqq.w = eWih1[r * 4 + 3] * sc;
        c.x = eWhh1[r * 4 + 0] * sc; c.y = eWhh1[r * 4 + 1] * sc;
        c.z = eWhh1[r * 4 + 2] * sc; c.w = eWhh1[r * 4 + 3] * sc;
        m.x = eWih0[r] * sc;
        m.y = (ebih0[r] + ebhh0[r]) * sc;
        m.z = (ebih1[r] + ebhh1[r]) * sc;
        m.w = 0.f;
        wsv[base + 0] = a; wsv[base + 1] = bqq; wsv[base + 2] = c; wsv[base + 3] = m;
    }
}

// 16 lanes per element: 4096*16 = 65536 threads = 1024 waves = 1 wave/SIMD.
// waves_per_eu(1,1): scheduler pressure limit = full 512-reg unified file,
// so the pinned weight set (~150 regs) stays resident instead of remat-loading.
__global__ __launch_bounds__(256) __attribute__((amdgpu_waves_per_eu(1, 1)))
void fused_kernel(
    const float* __restrict__ x,
    const float* __restrict__ fcW, const float* __restrict__ fcb,
    const float* __restrict__ ws, float* __restrict__ out)
{
    const int tid  = blockIdx.x * 256 + threadIdx.x;
    const int b    = tid >> 4;
    const int lane = tid & 15;
    const v4f* __restrict__ wsv = (const v4f*)ws;

    // =================== ENCODER (gate-row-parallel, H=4) ===================
    const int u4 = lane & 3;
    const int kk = lane >> 2;
    const float Ak = (kk == 2) ? 2.0f : 1.0f;
    const float Bk = (kk == 2) ? -1.0f : 0.0f;

    v4f ewh0 = wsv[ENC_BASE + lane * 4 + 0];
    v4f ewi1 = wsv[ENC_BASE + lane * 4 + 1];
    v4f ewh1 = wsv[ENC_BASE + lane * 4 + 2];
    v4f em   = wsv[ENC_BASE + lane * 4 + 3];
    asm volatile("" : "+v"(ewh0), "+v"(ewi1), "+v"(ewh1), "+v"(em));

    float h0v[4] = {0.f, 0.f, 0.f, 0.f};
    float h1v[4] = {0.f, 0.f, 0.f, 0.f};
    float c0 = 0.f, c1 = 0.f;
    float fw0, fw1;

    {
        const v4f* __restrict__ xq4 = (const v4f*)(x + (long)b * T_N);
        v4f xq = xq4[0];

        auto estep = [&](float xc) {
            float p = em.z;
            p = fmaf(ewh1.x, h1v[0], p); p = fmaf(ewh1.y, h1v[1], p);
            p = fmaf(ewh1.z, h1v[2], p); p = fmaf(ewh1.w, h1v[3], p);

            float g = fmaf(em.x, xc, em.y);
            g = fmaf(ewh0.x, h0v[0], g); g = fmaf(ewh0.y, h0v[1], g);
            g = fmaf(ewh0.z, h0v[2], g); g = fmaf(ewh0.w, h0v[3], g);
            float gate = act_ab(g, Ak, Bk);
            float fv = __shfl(gate, u4 + 4, 16);
            float gv = __shfl(gate, u4 + 8, 16);
            float ov = __shfl(gate, u4 + 12, 16);
            c0 = fmaf(fv, c0, gate * gv);
            float h0u = ov * tanh_nat(c0);
#pragma unroll
            for (int j = 0; j < 4; ++j) h0v[j] = __shfl(h0u, j, 16);

            float q = ewi1.x * h0v[0];
            q = fmaf(ewi1.y, h0v[1], q); q = fmaf(ewi1.z, h0v[2], q);
            q = fmaf(ewi1.w, h0v[3], q);
            float gate1 = act_ab(p + q, Ak, Bk);
            fv = __shfl(gate1, u4 + 4, 16);
            gv = __shfl(gate1, u4 + 8, 16);
            ov = __shfl(gate1, u4 + 12, 16);
            c1 = fmaf(fv, c1, gate1 * gv);
            float h1u = ov * tanh_nat(c1);
#pragma unroll
            for (int j = 0; j < 4; ++j) h1v[j] = __shfl(h1u, j, 16);
        };

        for (int tb = 0; tb < T_N / 4; ++tb) {
            v4f xn = (tb + 1 < T_N / 4) ? xq4[tb + 1] : xq;  // prefetch
            estep(xq.x); estep(xq.y); estep(xq.z); estep(xq.w);
            xq = xn;
        }

        fw0 = fcb[0]; fw1 = fcb[1];
#pragma unroll
        for (int j = 0; j < 4; ++j) {
            fw0 = fmaf(fcW[j], h1v[j], fw0);
            fw1 = fmaf(fcW[4 + j], h1v[j], fw1);
        }
        if (lane == 0) {
            out[FWD_OFF + b * 2 + 0] = fw0;
            out[FWD_OFF + b * 2 + 1] = fw1;
        }
    }

    // =================== DECODER (unit-parallel, H=10) ===================
    const int dbase = lane * 34;
    v4f wh0T[10], wi1T[10], wh1T[10];
#pragma unroll
    for (int j = 0; j < 10; ++j) {
        wh0T[j] = wsv[dbase + j];
        wi1T[j] = wsv[dbase + 10 + j];
        wh1T[j] = wsv[dbase + 20 + j];
    }
    v4f w0  = wsv[dbase + 30];
    v4f bb0 = wsv[dbase + 31];
    v4f bb1 = wsv[dbase + 32];
    v4f msc = wsv[dbase + 33];
    // Pin: loop uses asm outputs -> not rematerializable as loads.
    asm volatile("" : "+v"(wh0T[0]), "+v"(wh0T[1]), "+v"(wh0T[2]), "+v"(wh0T[3]), "+v"(wh0T[4]),
                      "+v"(wh0T[5]), "+v"(wh0T[6]), "+v"(wh0T[7]), "+v"(wh0T[8]), "+v"(wh0T[9]));
    asm volatile("" : "+v"(wi1T[0]), "+v"(wi1T[1]), "+v"(wi1T[2]), "+v"(wi1T[3]), "+v"(wi1T[4]),
                      "+v"(wi1T[5]), "+v"(wi1T[6]), "+v"(wi1T[7]), "+v"(wi1T[8]), "+v"(wi1T[9]));
    asm volatile("" : "+v"(wh1T[0]), "+v"(wh1T[1]), "+v"(wh1T[2]), "+v"(wh1T[3]), "+v"(wh1T[4]),
                      "+v"(wh1T[5]), "+v"(wh1T[6]), "+v"(wh1T[7]), "+v"(wh1T[8]), "+v"(wh1T[9]));
    asm volatile("" : "+v"(w0), "+v"(bb0), "+v"(bb1), "+v"(msc));

    float dh0[10], dh1[10];
#pragma unroll
    for (int j = 0; j < 10; ++j) {
        dh0[j] = (j < 4) ? h0v[j] : 0.f;
        dh1[j] = (j < 4) ? h1v[j] : 0.f;
    }
    float dc0 = (lane < 4) ? c0 : 0.f;
    float dc1 = (lane < 4) ? c1 : 0.f;

    float* __restrict__ noise_base = out + NOISE_OFF + b * T_N;
    float2* __restrict__ fin_base  = (float2*)out + b * T_N;

    float my_noise = 0.f;

    for (int t = 0; t < T_N; ++t) {
        const float inp = dh1[0];

        // L1 partial from previous h1 (independent of L0 chain)
        v4f p = bb1;
#pragma unroll
        for (int j = 0; j < 10; ++j) fma4(p, wh1T[j], dh1[j]);

        // L0 gates (4 gate rows of unit `lane` in one v4f accumulator)
        v4f g = bb0;
        fma4(g, w0, inp);
#pragma unroll
        for (int j = 0; j < 10; ++j) fma4(g, wh0T[j], dh0[j]);
        float iv = sig_acc(g.x), fv = sig_acc(g.y), gv = tanh_acc(g.z), ov = sig_acc(g.w);
        dc0 = fmaf(fv, dc0, iv * gv);
        const float h0u = ov * tanh_nat(dc0);
#pragma unroll
        for (int j = 0; j < 10; ++j) dh0[j] = __shfl(h0u, j, 16);

        // L1 gates (post-broadcast half accumulates into p)
#pragma unroll
        for (int j = 0; j < 10; ++j) fma4(p, wi1T[j], dh0[j]);
        iv = sig_acc(p.x); fv = sig_acc(p.y); gv = tanh_acc(p.z); ov = sig_acc(p.w);
        dc1 = fmaf(fv, dc1, iv * gv);
        const float h1u = ov * tanh_nat(dc1);
#pragma unroll
        for (int j = 0; j < 10; ++j) dh1[j] = __shfl(h1u, j, 16);

        // noise = outb0 + sum_u outw[u]*h1[u]: butterfly over the 16-group
        float contrib = msc.x * h1u;   // 0 on shadow lanes 10..15
        contrib += __shfl_xor(contrib, 1, 16);
        contrib += __shfl_xor(contrib, 2, 16);
        contrib += __shfl_xor(contrib, 4, 16);
        contrib += __shfl_xor(contrib, 8, 16);
        float nz = contrib + msc.y;

        // lane keeps t with t%16==lane; flush coalesced every 16 steps
        my_noise = ((t & 15) == lane) ? nz : my_noise;
        if ((t & 15) == 15) {
            const int off = (t - 15) + lane;
            noise_base[off] = my_noise;
            float2 fin;
            fin.x = my_noise + fw0;
            fin.y = my_noise + fw1;
            fin_base[off] = fin;
        }
    }
}

extern "C" void kernel_launch(void* const* d_in, const int* in_sizes, int n_in,
                              void* d_out, int out_size, void* d_ws, size_t ws_size,
                              hipStream_t stream) {
    const float* x     = (const float*)d_in[0];
    const float* eWih0 = (const float*)d_in[2];
    const float* eWhh0 = (const float*)d_in[3];
    const float* ebih0 = (const float*)d_in[4];
    const float* ebhh0 = (const float*)d_in[5];
    const float* eWih1 = (const float*)d_in[6];
    const float* eWhh1 = (const float*)d_in[7];
    const float* ebih1 = (const float*)d_in[8];
    const float* ebhh1 = (const float*)d_in[9];
    const float* dWih0 = (const float*)d_in[10];
    const float* dWhh0 = (const float*)d_in[11];
    const float* dbih0 = (const float*)d_in[12];
    const float* dbhh0 = (const float*)d_in[13];
    const float* dWih1 = (const float*)d_in[14];
    const float* dWhh1 = (const float*)d_in[15];
    const float* dbih1 = (const float*)d_in[16];
    const float* dbhh1 = (const float*)d_in[17];
    const float* fcW   = (const float*)d_in[18];
    const float* fcb   = (const float*)d_in[19];
    const float* outW  = (const float*)d_in[20];
    const float* outb  = (const float*)d_in[21];

    float* out = (float*)d_out;
    float* ws  = (float*)d_ws;

    prep_kernel<<<dim3(1), dim3(64), 0, stream>>>(
        eWih0, eWhh0, ebih0, ebhh0, eWih1, eWhh1, ebih1, ebhh1,
        dWih0, dWhh0, dbih0, dbhh0, dWih1, dWhh1, dbih1, dbhh1,
        outW, outb, ws);

    fused_kernel<<<dim3((B_N * 16) / 256), dim3(256), 0, stream>>>(
        x, fcW, fcb, ws, out);
}